// Round 6
// baseline (170.913 us; speedup 1.0000x reference)
//
#include <hip/hip_runtime.h>
#include <math.h>

#define BB 16
#define PP (768*768)        // 589824
#define NBINS 4096
#define CHUNKS 96           // blocks per image; pixels/block = 6144 (fits u16 fields)
#define KALL 176947         // int(P * 0.3)

#define LOV_LO (-17.0f)
#define LOV_RANGE 34.0f

typedef unsigned long long u64;

struct PAcc { float pos_sum, pos_w, tpx, sprx, mx, sum_t, n_tis, bce0; };   // 32 B
struct AccR { float lov_i, ft_i, ohem_i; unsigned posb; };                  // 16 B

__device__ inline float wred_sum(float v) {
  #pragma unroll
  for (int o = 32; o > 0; o >>= 1) v += __shfl_down(v, o, 64);
  return v;
}
__device__ inline float wred_max(float v) {
  #pragma unroll
  for (int o = 32; o > 0; o >>= 1) v = fmaxf(v, __shfl_down(v, o, 64));
  return v;
}

// ---------------- K1: fused pass; ONE LDS atomic per pixel ----------------
// hist1[bin] = count | pos<<16  (always)
// hist3p[bin/2] packed u16 pair = #(t==0 && m!=1) in bin  (atomic fires only when m!=1)
// negtis is reconstructed in k_reduce as (count - pos) - hist3.
__global__ __launch_bounds__(256) void k_main(const float* __restrict__ logits,
                                              const int* __restrict__ targets,
                                              const float* __restrict__ mask,
                                              PAcc* __restrict__ pacc,
                                              unsigned* __restrict__ partial1,
                                              unsigned* __restrict__ partial3)
{
  const int b = blockIdx.y;
  const int chunk = blockIdx.x;
  __shared__ unsigned hist1[NBINS];        // 16 KB
  __shared__ unsigned hist3p[NBINS / 2];   // 8 KB (packed u16 pairs)
  __shared__ float wsum[4][8];
  for (int i = threadIdx.x; i < NBINS; i += 256) hist1[i] = 0u;
  for (int i = threadIdx.x; i < NBINS / 2; i += 256) hist3p[i] = 0u;
  __syncthreads();

  const float4* l4 = (const float4*)(logits + (size_t)b * PP);
  const int4*   t4 = (const int4*)(targets + (size_t)b * PP);
  const float4* m4 = (const float4*)(mask + (size_t)b * PP);

  const float lov_scale = (float)NBINS / LOV_RANGE;

  float pos_sum = 0.f, pos_w = 0.f, tpa = 0.f, spra = 0.f, mx = 0.f;
  float sum_t = 0.f, n_tis = 0.f, bce0 = 0.f;

  // fallback loss_i[0] (chunk 0 / thread 0 only; block-sum propagates it)
  if (chunk == 0 && threadIdx.x == 0) {
    float l = logits[(size_t)b * PP];
    float tf = (float)targets[(size_t)b * PP];
    float m = mask[(size_t)b * PP];
    float ex = __expf(-fabsf(l));
    bce0 = (fmaxf(l, 0.f) + __logf(1.f + ex) - l * tf) * m;
  }

  const int per_chunk4 = (PP / CHUNKS) / 4;          // 1536
  const int base4 = chunk * per_chunk4;
  const int iters = per_chunk4 / 256;                // 6

  for (int it = 0; it < iters; ++it) {
    int i = base4 + it * 256 + threadIdx.x;
    float4 lv = l4[i]; int4 tv = t4[i]; float4 mv = m4[i];
    float ls[4] = {lv.x, lv.y, lv.z, lv.w};
    int   ts[4] = {tv.x, tv.y, tv.z, tv.w};
    float ms[4] = {mv.x, mv.y, mv.z, mv.w};
    #pragma unroll
    for (int c = 0; c < 4; ++c) {
      float l = ls[c]; int ti = ts[c]; float tf = (float)ti; float m = ms[c];
      float ex = __expf(-fabsf(l));                    // e^{-|l|}
      float lg = __logf(1.f + ex);                     // log1p(exp(-|l|)), 1+ex in (1,2]
      float loss = (fmaxf(l, 0.f) + lg - l * tf) * m;  // bce * mask
      float posw = tf * m;
      pos_sum = fmaf(loss, posw, pos_sum);
      pos_w  += posw;
      float pr = ((l >= 0.f) ? 1.f : ex) * __builtin_amdgcn_rcpf(1.f + ex);  // sigmoid
      spra += pr;
      tpa = fmaf(pr, tf, tpa);
      sum_t += tf;
      bool tis = (m == 1.0f);
      if (tis) { n_tis += 1.f; mx = fmaxf(mx, loss); }
      float s = fmaf(2.f, tf, -1.f);
      float e = fmaf(-l, s, 1.f);                      // lovasz error
      int bin = (int)((e - LOV_LO) * lov_scale);
      bin = bin < 0 ? 0 : (bin > NBINS - 1 ? NBINS - 1 : bin);
      atomicAdd(&hist1[bin], 1u | ((unsigned)ti << 16));
      if ((ti == 0) & !tis)                            // never fires when mask==1
        atomicAdd(&hist3p[bin >> 1], 1u << ((bin & 1) << 4));
    }
  }

  // block-level scalar reduction -> pacc (non-atomic)
  {
    float v0 = wred_sum(pos_sum), v1 = wred_sum(pos_w), v2 = wred_sum(tpa);
    float v3 = wred_sum(spra), v4 = wred_max(mx), v5 = wred_sum(sum_t);
    float v6 = wred_sum(n_tis), v7 = wred_sum(bce0);
    int w = threadIdx.x >> 6, lane = threadIdx.x & 63;
    if (lane == 0) {
      wsum[w][0] = v0; wsum[w][1] = v1; wsum[w][2] = v2; wsum[w][3] = v3;
      wsum[w][4] = v4; wsum[w][5] = v5; wsum[w][6] = v6; wsum[w][7] = v7;
    }
  }
  __syncthreads();
  if (threadIdx.x == 0) {
    PAcc r;
    r.pos_sum = wsum[0][0] + wsum[1][0] + wsum[2][0] + wsum[3][0];
    r.pos_w   = wsum[0][1] + wsum[1][1] + wsum[2][1] + wsum[3][1];
    r.tpx     = wsum[0][2] + wsum[1][2] + wsum[2][2] + wsum[3][2];
    r.sprx    = wsum[0][3] + wsum[1][3] + wsum[2][3] + wsum[3][3];
    r.mx      = fmaxf(fmaxf(wsum[0][4], wsum[1][4]), fmaxf(wsum[2][4], wsum[3][4]));
    r.sum_t   = wsum[0][5] + wsum[1][5] + wsum[2][5] + wsum[3][5];
    r.n_tis   = wsum[0][6] + wsum[1][6] + wsum[2][6] + wsum[3][6];
    r.bce0    = wsum[0][7] + wsum[1][7] + wsum[2][7] + wsum[3][7];
    pacc[(size_t)b * CHUNKS + chunk] = r;
  }

  // non-atomic coalesced flush
  {
    unsigned* d1 = partial1 + ((size_t)b * CHUNKS + chunk) * NBINS;
    for (int i = threadIdx.x; i < NBINS; i += 256) d1[i] = hist1[i];
    unsigned* d3 = partial3 + ((size_t)b * CHUNKS + chunk) * (NBINS / 2);
    for (int i = threadIdx.x; i < NBINS / 2; i += 256) d3[i] = hist3p[i];
  }
}

// ---------------- K1b: reduce partials -> packed per-image hist; reduce pacc; zero ticket ----------------
__global__ __launch_bounds__(256) void k_reduce(const unsigned* __restrict__ partial1,
                                                const unsigned* __restrict__ partial3,
                                                u64* __restrict__ ghist,
                                                const PAcc* __restrict__ pacc,
                                                PAcc* __restrict__ accImg,
                                                unsigned* __restrict__ ticket)
{
  const int img = blockIdx.y;          // 16
  const int slice = blockIdx.x;        // NBINS/256 = 16
  const int bin = slice * 256 + threadIdx.x;
  const unsigned* s1 = partial1 + (size_t)img * CHUNKS * NBINS + bin;
  const unsigned* s3 = partial3 + (size_t)img * CHUNKS * (NBINS / 2) + (bin >> 1);
  const unsigned sh3 = (bin & 1) << 4;
  unsigned c = 0, q = 0, n0 = 0;
  #pragma unroll 4
  for (int p = 0; p < CHUNKS; ++p) {
    unsigned v = s1[(size_t)p * NBINS];
    c += v & 0xFFFFu; q += v >> 16;
    n0 += (s3[(size_t)p * (NBINS / 2)] >> sh3) & 0xFFFFu;
  }
  unsigned negtis = (c - q) - n0;      // #(t==0 && m==1) in bin
  ghist[(size_t)img * NBINS + bin] =
      (u64)c | ((u64)q << 20) | ((u64)negtis << 40);

  if (slice == 0 && threadIdx.x < 128) {
    int t = threadIdx.x;
    PAcc v;
    if (t < CHUNKS) v = pacc[(size_t)img * CHUNKS + t];
    else { v.pos_sum = v.pos_w = v.tpx = v.sprx = v.mx = v.sum_t = v.n_tis = v.bce0 = 0.f; }
    v.pos_sum = wred_sum(v.pos_sum); v.pos_w = wred_sum(v.pos_w);
    v.tpx = wred_sum(v.tpx); v.sprx = wred_sum(v.sprx);
    v.mx = wred_max(v.mx); v.sum_t = wred_sum(v.sum_t);
    v.n_tis = wred_sum(v.n_tis); v.bce0 = wred_sum(v.bce0);
    __shared__ PAcc half[2];
    if ((t & 63) == 0) half[t >> 6] = v;
    __syncthreads();
    if (t == 0) {
      PAcc r = half[0], h = half[1];
      r.pos_sum += h.pos_sum; r.pos_w += h.pos_w; r.tpx += h.tpx; r.sprx += h.sprx;
      r.mx = fmaxf(r.mx, h.mx); r.sum_t += h.sum_t; r.n_tis += h.n_tis; r.bce0 += h.bce0;
      accImg[img] = r;
    }
  }
  if (slice == 0 && img == 0 && threadIdx.x == 0) *ticket = 0u;
}

// ---------------- K2: per-image descending walk (lovasz + OHEM) + last-block final combine ----------------
__global__ __launch_bounds__(256) void k_scan(const PAcc* __restrict__ accImg,
                                              const u64* __restrict__ ghist,
                                              AccR* __restrict__ acc,
                                              unsigned* __restrict__ ticket,
                                              float* __restrict__ out)
{
  const int b = blockIdx.x;
  const int t = threadIdx.x;
  __shared__ unsigned sA[256], sB[256], sC[256];
  __shared__ float sf[256], sg[256];
  __shared__ unsigned ng_total_sh;

  const u64* gh = ghist + (size_t)b * NBINS;
  const PAcc a = accImg[b];

  const unsigned sum_t = (unsigned)a.sum_t;
  const float p = (float)sum_t;
  const bool has_pos = sum_t > 0;
  const unsigned n_neg_total = (unsigned)PP - sum_t;
  const int CH = NBINS / 256;          // 16 bins per thread
  const float lov_d = LOV_RANGE / (float)NBINS;

  int n_pos = (int)a.pos_w;            // truncation like astype(int32)
  int n_remain = KALL - n_pos; if (n_remain < 0) n_remain = 0;

  u64 loc[16];
  unsigned tc = 0, tq = 0, tn = 0;
  #pragma unroll
  for (int k = 0; k < 16; ++k) {
    u64 v = gh[NBINS - 1 - (t * CH + k)];
    loc[k] = v;
    tc += (unsigned)(v & 0xFFFFFu);
    tq += (unsigned)((v >> 20) & 0xFFFFFu);
    tn += (unsigned)((v >> 40) & 0xFFFFFu);
  }
  sA[t] = tc; sB[t] = tq; sC[t] = tn;
  __syncthreads();
  if (t == 0) {
    unsigned aI = 0, aC = 0, aN = 0;
    for (int i = 0; i < 256; i++) {
      unsigned ci = sA[i], qi = sB[i], ni = sC[i];
      sA[i] = aI; sB[i] = aC; sC[i] = aN;
      aI += ci; aC += qi; aN += ni;
    }
    ng_total_sh = aN;
  }
  __syncthreads();

  float lov_local = 0.f, ns_local = 0.f;
  {
    unsigned I = sA[t], C = sB[t], NG = sC[t];
    float Jprev = has_pos ? (1.f - (p - (float)C) / (p + (float)I - (float)C)) : 0.f;
    #pragma unroll 4
    for (int k = 0; k < 16; ++k) {
      int j = NBINS - 1 - (t * CH + k);
      u64 v = loc[k];
      unsigned c = (unsigned)(v & 0xFFFFFu);
      if (c) {
        unsigned q = (unsigned)((v >> 20) & 0xFFFFFu);
        unsigned ng = (unsigned)((v >> 40) & 0xFFFFFu);
        float e = LOV_LO + ((float)j + 0.5f) * lov_d;
        if (has_pos) {
          float re = fmaxf(e, 0.f);
          if (n_neg_total > 0) {
            I += c; C += q;
            float Jb = 1.f - (p - (float)C) / (p + (float)I - (float)C);
            lov_local += re * (Jb - Jprev);
            Jprev = Jb;
          } else {
            double hi = (double)I + (double)c;
            double s = (hi * (hi + 1.0) - (double)I * ((double)I + 1.0)) * 0.5 / (double)p;
            lov_local += re * (float)s;
            I += c;
          }
        }
        if (n_remain > 0 && ng) {
          long long rem = (long long)n_remain - (long long)NG;
          unsigned take = rem <= 0 ? 0u : (rem >= (long long)ng ? ng : (unsigned)rem);
          if (take) {
            float l = e - 1.f;                         // negatives: e = 1 + l
            float nloss = fmaxf(l, 0.f) + __logf(1.f + __expf(-fabsf(l)));
            ns_local += (float)take * nloss;
          }
          NG += ng;
        }
      }
    }
  }
  sf[t] = lov_local; sg[t] = ns_local; __syncthreads();
  for (int off = 128; off > 0; off >>= 1) {
    if (t < off) { sf[t] += sf[t + off]; sg[t] += sg[t + off]; }
    __syncthreads();
  }

  if (t == 0) {
    float lov = sf[0];
    float neg_sum = sg[0];
    unsigned kept = (n_remain > 0)
        ? ((unsigned)n_remain < ng_total_sh ? (unsigned)n_remain : ng_total_sh) : 0u;
    float cnt = (float)n_pos + (float)kept;
    float ohem;
    if (cnt > 0.f) ohem = (a.pos_sum + neg_sum) / cnt;
    else ohem = (a.n_tis > 0.f) ? a.mx : a.bce0;
    float tp = a.tpx;
    float fn = p - tp;
    float fp = a.sprx - tp;
    float tv = (tp + 1e-6f) / (tp + 0.3f * fn + 0.7f * fp + 1e-6f);
    float ft = powf(fmaxf(1.f - tv, 0.f), 1.33f);
    acc[b].lov_i = lov; acc[b].ft_i = ft; acc[b].ohem_i = ohem;
    acc[b].posb = has_pos ? 1u : 0u;

    __threadfence();
    unsigned ret = atomicAdd(ticket, 1u);
    if (ret == BB - 1) {                 // last block: final combine
      __threadfence();
      volatile AccR* va = acc;
      float os = 0.f, fts = 0.f, lvs = 0.f; int np = 0;
      for (int i = 0; i < BB; i++) {
        os += va[i].ohem_i;
        if (va[i].posb) { np++; fts += va[i].ft_i; lvs += va[i].lov_i; }
      }
      float denom = (np > 0) ? (float)np : 1.f;
      float r = os / (float)BB;
      if (np > 0) r += fts / denom + 0.2f * (lvs / denom);
      out[0] = r;
    }
  }
}

extern "C" void kernel_launch(void* const* d_in, const int* in_sizes, int n_in,
                              void* d_out, int out_size, void* d_ws, size_t ws_size,
                              hipStream_t stream) {
  const float* logits  = (const float*)d_in[0];
  const int*   targets = (const int*)d_in[1];
  const float* mask    = (const float*)d_in[2];
  float* out = (float*)d_out;

  char* ws = (char*)d_ws;
  AccR*     acc      = (AccR*)ws;                        // 256 B
  unsigned* ticket   = (unsigned*)(ws + 256);            // 4 B
  PAcc*     accImg   = (PAcc*)(ws + 512);                // 512 B
  PAcc*     pacc     = (PAcc*)(ws + 1024);               // 16*96*32 = 48 KB
  u64*      ghist    = (u64*)(ws + (64 << 10));          // 16*4096*8 = 512 KB
  unsigned* partial1 = (unsigned*)(ws + (1 << 20));      // 16*96*4096*4 = 25.2 MB
  unsigned* partial3 = (unsigned*)(ws + (1 << 20) + (size_t)BB * CHUNKS * NBINS * 4);  // 12.6 MB
  (void)in_sizes; (void)n_in; (void)out_size; (void)ws_size;

  // no memset needed: every ws location read this launch is written first

  dim3 g1(CHUNKS, BB, 1);        // 1536 blocks, 24KB LDS -> 6 blocks/CU
  k_main<<<g1, 256, 0, stream>>>(logits, targets, mask, pacc, partial1, partial3);
  dim3 g2(NBINS / 256, BB, 1);   // 16 x 16 = 256 blocks
  k_reduce<<<g2, 256, 0, stream>>>(partial1, partial3, ghist, pacc, accImg, ticket);
  k_scan<<<BB, 256, 0, stream>>>(accImg, ghist, acc, ticket, out);
}